// Round 4
// baseline (345.231 us; speedup 1.0000x reference)
//
#include <hip/hip_runtime.h>

typedef __bf16 bf16x8 __attribute__((ext_vector_type(8)));
typedef float floatx4 __attribute__((ext_vector_type(4)));

#define EPSF 1e-6f

__device__ inline unsigned short f2bf(float f) {  // RNE
  union { float f; unsigned u; } x; x.f = f;
  unsigned r = x.u + 0x7FFFu + ((x.u >> 16) & 1u);
  return (unsigned short)(r >> 16);
}
__device__ inline float bf2f(unsigned short u) {
  union { unsigned u; float f; } x; x.u = ((unsigned)u) << 16;
  return x.f;
}
// pack two f32 -> bf16x2 dword, round-half-up
__device__ inline unsigned pk2bf(float lo, float hi) {
  union { float f; unsigned u; } a, b; a.f = lo; b.f = hi;
  unsigned ua = a.u + 0x8000u, ub = b.u + 0x8000u;
  return (ub & 0xFFFF0000u) | (ua >> 16);
}

__device__ inline floatx4 mfma16(bf16x8 a, bf16x8 b, floatx4 c) {
  return __builtin_amdgcn_mfma_f32_16x16x32_bf16(a, b, c, 0, 0, 0);
}

__device__ inline void gll16(const unsigned short* g, unsigned short* l) {
  __builtin_amdgcn_global_load_lds((__attribute__((address_space(1))) void*)g,
                                   (__attribute__((address_space(3))) void*)l, 16, 0, 0);
}

// ---------- fp32 -> bf16 cast; elements i < n_scaled get *0.125 (SCALE folded into Q weights) ----------
__global__ __launch_bounds__(256) void cast_bf16_kernel(const float* __restrict__ in,
                                                        unsigned short* __restrict__ out,
                                                        int n, int n_scaled) {
  int i = (blockIdx.x * 256 + threadIdx.x) * 8;
  if (i >= n) return;
  const float s = (i < n_scaled) ? 0.125f : 1.0f;
  float4 v0 = *(const float4*)(in + i);
  float4 v1 = *(const float4*)(in + i + 4);
  __align__(16) unsigned short o[8] = {
      f2bf(v0.x * s), f2bf(v0.y * s), f2bf(v0.z * s), f2bf(v0.w * s),
      f2bf(v1.x * s), f2bf(v1.y * s), f2bf(v1.z * s), f2bf(v1.w * s)};
  *(float4*)(out + i) = *(float4*)o;
}

// ---------- policy -> permuted bf16 vector pbf[b][g], g-chunk col' = (c%16)*2 + c/16 ----------
__global__ __launch_bounds__(256) void policy_pack(const float* __restrict__ policy,
                                                   unsigned short* __restrict__ pbf) {
  int idx = blockIdx.x * 256 + threadIdx.x;  // 8192
  int b = idx >> 10, g = idx & 1023;
  int chunk = g >> 5, w = g & 31;
  int c = (chunk << 5) + (w >> 1) + ((w & 1) << 4);
  pbf[idx] = f2bf(policy[b * 1024 + c]);
}

// ---------- bf16 GEMM: C[M,N] = A[M,K]*Bt[N,K]^T ; BN = 128 or 64 (J = BN/32 col-tiles/wave) ----------
template <int EP, int BN>
__global__ __launch_bounds__(256, 3) void gemm_bt(const unsigned short* __restrict__ A,
                                                  const unsigned short* __restrict__ Bt,
                                                  void* __restrict__ Cout,
                                                  const float* __restrict__ bias,
                                                  int M, int N, int K) {
  constexpr int J = BN / 32;
  __shared__ __align__(16) unsigned short sA[128 * 32];
  __shared__ __align__(16) unsigned short sB[BN * 32];
  const int m0 = blockIdx.y * 128, n0 = blockIdx.x * BN;
  const int tid = threadIdx.x;
  const int lane = tid & 63, wave = tid >> 6;
  const int qd = lane >> 4, l15 = lane & 15;
  const int wr = (wave >> 1) * 64, wc = (wave & 1) * (BN / 2);
  const int srow = tid >> 2, scol = (tid & 3) * 8;
  const unsigned short* Ag = A + (long)(m0 + srow) * K + scol;
  const unsigned short* Bg = Bt + (long)(n0 + srow) * K + scol;
  unsigned short* sAp = &sA[wave * 512];
  unsigned short* sBp = &sB[wave * 512];
  floatx4 acc[4][J] = {};
  for (int k0 = 0; k0 < K; k0 += 32) {
    __syncthreads();
    gll16(Ag + k0, sAp);
    gll16(Ag + (long)64 * K + k0, sAp + 2048);
    gll16(Bg + k0, sBp);
    if (BN == 128) gll16(Bg + (long)64 * K + k0, sBp + 2048);
    __syncthreads();
    bf16x8 af[4], bf[J];
#pragma unroll
    for (int i = 0; i < 4; i++) af[i] = *(const bf16x8*)&sA[(wr + i * 16 + l15) * 32 + qd * 8];
#pragma unroll
    for (int j = 0; j < J; j++) bf[j] = *(const bf16x8*)&sB[(wc + j * 16 + l15) * 32 + qd * 8];
#pragma unroll
    for (int i = 0; i < 4; i++)
#pragma unroll
      for (int j = 0; j < J; j++) acc[i][j] = mfma16(af[i], bf[j], acc[i][j]);
  }
#pragma unroll
  for (int i = 0; i < 4; i++) {
#pragma unroll
    for (int j = 0; j < J; j++) {
      const int col = n0 + wc + j * 16 + l15;
#pragma unroll
      for (int r = 0; r < 4; r++) {
        const int row = m0 + wr + i * 16 + qd * 4 + r;
        if (EP == 0) {
          ((unsigned short*)Cout)[(long)row * N + col] = f2bf(acc[i][j][r]);
        } else {
          ((float*)Cout)[(long)row * N + col] = acc[i][j][r] + bias[col];
        }
      }
    }
  }
}

// ---------- V transpose + policy fold + k-permute: vTp[bh][d][g] = bf16(V[c(g)][d] * p[c(g)]) ----------
__global__ __launch_bounds__(256) void transpose_v(const unsigned short* __restrict__ qkv,
                                                   const float* __restrict__ policy,
                                                   unsigned short* __restrict__ vTp) {
  __shared__ unsigned short tile[64][72];
  __shared__ float sPol[64];
  const int bh = blockIdx.y;
  const int b = bh / 12, h = bh % 12;
  const int n0 = blockIdx.x * 64;
  const int t = threadIdx.x;
  if (t < 64) sPol[t] = policy[b * 1024 + n0 + t];
  {
    const int nr = t >> 2, dc = (t & 3) * 16;
    const unsigned short* src = qkv + (long)(b * 1024 + n0 + nr) * 2304 + 2 * 768 + h * 64 + dc;
    float4 v0 = *(const float4*)src;
    float4 v1 = *(const float4*)(src + 8);
    *(float4*)&tile[nr][dc] = v0;
    *(float4*)&tile[nr][dc + 8] = v1;
  }
  __syncthreads();
  {
    const int d = t >> 2, nc = (t & 3) * 16;
    __align__(16) unsigned short o[16];
#pragma unroll
    for (int jj = 0; jj < 16; jj++) {
      const int cc = nc + jj;
      const int w = cc & 31;
      const int cl = (cc & 32) + (w >> 1) + ((w & 1) << 4);
      o[jj] = f2bf(bf2f(tile[cl][d]) * sPol[cl]);
    }
    unsigned short* dst = vTp + (long)(bh * 64 + d) * 1024 + n0 + nc;
    *(float4*)dst = *(float4*)&o[0];
    *(float4*)(dst + 8) = *(float4*)&o[8];
  }
}

// ---------- attention v4: 16 q-rows/wave, 6 blocks/CU, double-buffered sP, no barriers ----------
__global__ __launch_bounds__(256, 6) void attn_kernel(const unsigned short* __restrict__ qkv,
                                                      const unsigned short* __restrict__ vTp,
                                                      const unsigned short* __restrict__ pbf,
                                                      const float* __restrict__ policy,
                                                      unsigned short* __restrict__ aout) {
  __shared__ __align__(16) unsigned short sP[4][2][640];  // [wave][dbuf][16 x 40]
  __shared__ float sD[4][16];
  const int bid = blockIdx.x;
  const int bh = bid % 96, qt = bid / 96;  // bh-fast for XCD L2 locality
  const int b = bh / 12, h = bh % 12;
  const int wave = threadIdx.x >> 6, lane = threadIdx.x & 63;
  const int qd = lane >> 4, l15 = lane & 15;
  const int q0 = qt * 64 + wave * 16;
  const unsigned short* qb = qkv + (long)(b * 1024 + q0 + l15) * 2304 + h * 64 + qd * 8;
  bf16x8 qf0 = *(const bf16x8*)qb;  // Q pre-scaled by 0.125
  bf16x8 qf1 = *(const bf16x8*)(qb + 32);
  const unsigned short* kbase = qkv + (long)(b * 1024 + l15) * 2304 + 768 + h * 64 + qd * 8;
  const unsigned short* vbase = vTp + (long)bh * 65536 + qd * 8;
  const unsigned short* pvb = pbf + b * 1024 + qd * 8;
  floatx4 O[4] = {};
  floatx4 Dl = {};
  for (int it = 0; it < 32; ++it) {
    const int c0 = it * 32;
    const unsigned short* kp = kbase + (long)c0 * 2304;
    bf16x8 k00 = *(const bf16x8*)kp;
    bf16x8 k01 = *(const bf16x8*)(kp + 32);
    bf16x8 k10 = *(const bf16x8*)(kp + (long)16 * 2304);
    bf16x8 k11 = *(const bf16x8*)(kp + (long)16 * 2304 + 32);
    bf16x8 pv = *(const bf16x8*)(pvb + c0);
    floatx4 z = {0.f, 0.f, 0.f, 0.f};
    floatx4 s0 = mfma16(qf1, k01, mfma16(qf0, k00, z));
    floatx4 s1 = mfma16(qf1, k11, mfma16(qf0, k10, z));
    unsigned short* sp = &sP[wave][it & 1][0];
#pragma unroll
    for (int r = 0; r < 4; r++)
      ((unsigned*)sp)[(qd * 4 + r) * 20 + l15] = pk2bf(__expf(s0[r]), __expf(s1[r]));
    bf16x8 pf = *(const bf16x8*)&sp[l15 * 40 + qd * 8];
    bf16x8 vf0 = *(const bf16x8*)(vbase + (long)l15 * 1024 + c0);
    bf16x8 vf1 = *(const bf16x8*)(vbase + (long)(16 + l15) * 1024 + c0);
    bf16x8 vf2 = *(const bf16x8*)(vbase + (long)(32 + l15) * 1024 + c0);
    bf16x8 vf3 = *(const bf16x8*)(vbase + (long)(48 + l15) * 1024 + c0);
    Dl = mfma16(pf, pv, Dl);
    O[0] = mfma16(pf, vf0, O[0]);
    O[1] = mfma16(pf, vf1, O[1]);
    O[2] = mfma16(pf, vf2, O[2]);
    O[3] = mfma16(pf, vf3, O[3]);
  }
  // ---- diagonal correction: O[q] += e_qq(1-p_q) V[q]; l_q += e_qq(1-p_q) ----
  {
    const unsigned short* kd = kbase + (long)q0 * 2304;  // K row q0+l15
    bf16x8 kd0 = *(const bf16x8*)kd;
    bf16x8 kd1 = *(const bf16x8*)(kd + 32);
    float part = 0.f;
#pragma unroll
    for (int jj = 0; jj < 8; jj++)
      part += (float)qf0[jj] * (float)kd0[jj] + (float)qf1[jj] * (float)kd1[jj];
    part += __shfl_xor(part, 16);
    part += __shfl_xor(part, 32);
    if (qd == 0) {
      const float p0 = policy[b * 1024 + q0 + l15];
      sD[wave][l15] = __expf(part) * (1.0f - p0);
    }
    const unsigned short* vdiag = qkv + (long)(b * 1024 + q0) * 2304 + 1536 + h * 64 + l15;
#pragma unroll
    for (int r = 0; r < 4; r++) {
      const int row = qd * 4 + r;
      const float cv = sD[wave][row];
#pragma unroll
      for (int j = 0; j < 4; j++)
        O[j][r] += cv * bf2f(vdiag[(long)row * 2304 + j * 16]);
      Dl[r] += cv;
    }
  }
  const long ob = (long)(b * 1024 + q0 + qd * 4) * 768 + h * 64 + l15;
#pragma unroll
  for (int r = 0; r < 4; r++) {
    const float li = 1.0f / (Dl[r] + EPSF);
#pragma unroll
    for (int j = 0; j < 4; j++)
      aout[ob + (long)r * 768 + j * 16] = f2bf(O[j][r] * li);
  }
}

extern "C" void kernel_launch(void* const* d_in, const int* in_sizes, int n_in,
                              void* d_out, int out_size, void* d_ws, size_t ws_size,
                              hipStream_t stream) {
  const float* x      = (const float*)d_in[0];   // [8,1024,768]
  const float* policy = (const float*)d_in[1];   // [8,1024,1]
  const float* qkv_w  = (const float*)d_in[2];   // [2304,768]
  const float* proj_w = (const float*)d_in[3];   // [768,768]
  const float* proj_b = (const float*)d_in[4];   // [768]
  float* out = (float*)d_out;                    // [8,1024,768] fp32

  char* ws = (char*)d_ws;
  unsigned short* xb    = (unsigned short*)(ws + 0);         // 12,582,912 B
  unsigned short* wqkv  = (unsigned short*)(ws + 12582912);  //  3,538,944 B
  unsigned short* wproj = (unsigned short*)(ws + 16121856);  //  1,179,648 B
  unsigned short* qkvb  = (unsigned short*)(ws + 17301504);  // 37,748,736 B
  unsigned short* vTp   = (unsigned short*)(ws + 55050240);  // 12,582,912 B
  unsigned short* aoutb = (unsigned short*)(ws + 67633152);  // 12,582,912 B
  unsigned short* pbf   = (unsigned short*)(ws + 80216064);  //     16,384 B

  cast_bf16_kernel<<<3072, 256, 0, stream>>>(x, xb, 6291456, 0);
  cast_bf16_kernel<<<864, 256, 0, stream>>>(qkv_w, wqkv, 1769472, 589824);  // Q rows *0.125
  cast_bf16_kernel<<<288, 256, 0, stream>>>(proj_w, wproj, 589824, 0);
  policy_pack<<<32, 256, 0, stream>>>(policy, pbf);
  gemm_bt<0, 128><<<dim3(18, 64), 256, 0, stream>>>(xb, wqkv, qkvb, nullptr, 8192, 2304, 768);
  transpose_v<<<dim3(16, 96), 256, 0, stream>>>(qkvb, policy, vTp);
  attn_kernel<<<dim3(1536), 256, 0, stream>>>(qkvb, vTp, pbf, policy, aoutb);
  gemm_bt<1, 64><<<dim3(12, 64), 256, 0, stream>>>(aoutb, wproj, out, proj_b, 8192, 768, 768);
}

// Round 6
// 211.878 us; speedup vs baseline: 1.6294x; 1.6294x over previous
//
#include <hip/hip_runtime.h>

typedef __bf16 bf16x8 __attribute__((ext_vector_type(8)));
typedef float floatx4 __attribute__((ext_vector_type(4)));

#define EPSF 1e-6f

__device__ inline unsigned short f2bf(float f) {  // RNE
  union { float f; unsigned u; } x; x.f = f;
  unsigned r = x.u + 0x7FFFu + ((x.u >> 16) & 1u);
  return (unsigned short)(r >> 16);
}
__device__ inline float bf2f(unsigned short u) {
  union { unsigned u; float f; } x; x.u = ((unsigned)u) << 16;
  return x.f;
}
// pack two f32 -> bf16x2 dword, round-half-up
__device__ inline unsigned pk2bf(float lo, float hi) {
  union { float f; unsigned u; } a, b; a.f = lo; b.f = hi;
  unsigned ua = a.u + 0x8000u, ub = b.u + 0x8000u;
  return (ub & 0xFFFF0000u) | (ua >> 16);
}

__device__ inline floatx4 mfma16(bf16x8 a, bf16x8 b, floatx4 c) {
  return __builtin_amdgcn_mfma_f32_16x16x32_bf16(a, b, c, 0, 0, 0);
}

__device__ inline void gll16(const unsigned short* g, unsigned short* l) {
  __builtin_amdgcn_global_load_lds((__attribute__((address_space(1))) void*)g,
                                   (__attribute__((address_space(3))) void*)l, 16, 0, 0);
}

// ---------- fp32 -> bf16 cast; elements i < n_scaled get *0.125*log2(e) (softmax scale + exp2 fold) ----------
__global__ __launch_bounds__(256) void cast_bf16_kernel(const float* __restrict__ in,
                                                        unsigned short* __restrict__ out,
                                                        int n, int n_scaled) {
  int i = (blockIdx.x * 256 + threadIdx.x) * 8;
  if (i >= n) return;
  const float s = (i < n_scaled) ? 0.18033688011112042f : 1.0f;  // 0.125 * log2(e)
  float4 v0 = *(const float4*)(in + i);
  float4 v1 = *(const float4*)(in + i + 4);
  __align__(16) unsigned short o[8] = {
      f2bf(v0.x * s), f2bf(v0.y * s), f2bf(v0.z * s), f2bf(v0.w * s),
      f2bf(v1.x * s), f2bf(v1.y * s), f2bf(v1.z * s), f2bf(v1.w * s)};
  *(float4*)(out + i) = *(float4*)o;
}

// ---------- policy -> permuted bf16 vector pbf[b][g], g-chunk col' = (c%16)*2 + c/16 ----------
__global__ __launch_bounds__(256) void policy_pack(const float* __restrict__ policy,
                                                   unsigned short* __restrict__ pbf) {
  int idx = blockIdx.x * 256 + threadIdx.x;  // 8192
  int b = idx >> 10, g = idx & 1023;
  int chunk = g >> 5, w = g & 31;
  int c = (chunk << 5) + (w >> 1) + ((w & 1) << 4);
  pbf[idx] = f2bf(policy[b * 1024 + c]);
}

// ---------- bf16 GEMM: C[M,N] = A[M,K]*Bt[N,K]^T ; BK=64, XOR-swizzled LDS, BN = 128 or 64 ----------
template <int EP, int BN>
__global__ __launch_bounds__(256, 3) void gemm_bt(const unsigned short* __restrict__ A,
                                                  const unsigned short* __restrict__ Bt,
                                                  void* __restrict__ Cout,
                                                  const float* __restrict__ bias,
                                                  int M, int N, int K) {
  constexpr int J = BN / 32;
  __shared__ __align__(16) unsigned short sA[128 * 64];
  __shared__ __align__(16) unsigned short sB[BN * 64];
  const int m0 = blockIdx.y * 128, n0 = blockIdx.x * BN;
  const int tid = threadIdx.x;
  const int lane = tid & 63, wave = tid >> 6;
  const int qd = lane >> 4, l15 = lane & 15;
  const int wr = (wave >> 1) * 64, wc = (wave & 1) * (BN / 2);
  // staging: block m = p*32 + (tid>>3), col-block cb = (tid&7) ^ (row&7)
  const int srow = tid >> 3;
  const int scb = (tid & 7) ^ (srow & 7);
  const unsigned short* Ag = A + (long)(m0 + srow) * K + scb * 8;
  const unsigned short* Bg = Bt + (long)(n0 + srow) * K + scb * 8;
  const int x7 = l15 & 7;
  floatx4 acc[4][J] = {};
  for (int k0 = 0; k0 < K; k0 += 64) {
    __syncthreads();
#pragma unroll
    for (int p = 0; p < 4; p++) gll16(Ag + (long)(p * 32) * K + k0, sA + p * 2048 + wave * 512);
#pragma unroll
    for (int p = 0; p < J; p++) gll16(Bg + (long)(p * 32) * K + k0, sB + p * 2048 + wave * 512);
    __syncthreads();
#pragma unroll
    for (int s = 0; s < 2; s++) {
      const int cw = ((s * 4 + qd) ^ x7) * 8;
      bf16x8 af[4], bf[J];
#pragma unroll
      for (int i = 0; i < 4; i++) af[i] = *(const bf16x8*)&sA[(wr + i * 16 + l15) * 64 + cw];
#pragma unroll
      for (int j = 0; j < J; j++) bf[j] = *(const bf16x8*)&sB[(wc + j * 16 + l15) * 64 + cw];
#pragma unroll
      for (int i = 0; i < 4; i++)
#pragma unroll
        for (int j = 0; j < J; j++) acc[i][j] = mfma16(af[i], bf[j], acc[i][j]);
    }
  }
#pragma unroll
  for (int i = 0; i < 4; i++) {
#pragma unroll
    for (int j = 0; j < J; j++) {
      const int col = n0 + wc + j * 16 + l15;
#pragma unroll
      for (int r = 0; r < 4; r++) {
        const int row = m0 + wr + i * 16 + qd * 4 + r;
        if (EP == 0) {
          ((unsigned short*)Cout)[(long)row * N + col] = f2bf(acc[i][j][r]);
        } else {
          ((float*)Cout)[(long)row * N + col] = acc[i][j][r] + bias[col];
        }
      }
    }
  }
}

// ---------- V transpose + policy fold + k-permute: vTp[bh][d][g] = bf16(V[c(g)][d] * p[c(g)]) ----------
__global__ __launch_bounds__(256) void transpose_v(const unsigned short* __restrict__ qkv,
                                                   const float* __restrict__ policy,
                                                   unsigned short* __restrict__ vTp) {
  __shared__ unsigned short tile[64][72];
  __shared__ float sPol[64];
  const int bh = blockIdx.y;
  const int b = bh / 12, h = bh % 12;
  const int n0 = blockIdx.x * 64;
  const int t = threadIdx.x;
  if (t < 64) sPol[t] = policy[b * 1024 + n0 + t];
  {
    const int nr = t >> 2, dc = (t & 3) * 16;
    const unsigned short* src = qkv + (long)(b * 1024 + n0 + nr) * 2304 + 2 * 768 + h * 64 + dc;
    float4 v0 = *(const float4*)src;
    float4 v1 = *(const float4*)(src + 8);
    *(float4*)&tile[nr][dc] = v0;
    *(float4*)&tile[nr][dc + 8] = v1;
  }
  __syncthreads();
  {
    const int d = t >> 2, nc = (t & 3) * 16;
    __align__(16) unsigned short o[16];
#pragma unroll
    for (int jj = 0; jj < 16; jj++) {
      const int cc = nc + jj;
      const int w = cc & 31;
      const int cl = (cc & 32) + (w >> 1) + ((w & 1) << 4);
      o[jj] = f2bf(bf2f(tile[cl][d]) * sPol[cl]);
    }
    unsigned short* dst = vTp + (long)(bh * 64 + d) * 1024 + n0 + nc;
    *(float4*)dst = *(float4*)&o[0];
    *(float4*)(dst + 8) = *(float4*)&o[8];
  }
}

// ---------- attention v5b: 32 q-rows/wave, LDS-staged K/V via global_load_lds, fixed sP layout ----------
__global__ __launch_bounds__(256, 3) void attn_kernel(const unsigned short* __restrict__ qkv,
                                                      const unsigned short* __restrict__ vTp,
                                                      const unsigned short* __restrict__ pbf,
                                                      const float* __restrict__ policy,
                                                      unsigned short* __restrict__ aout) {
  __shared__ __align__(16) unsigned short sK[32 * 64];       // K chunk, slot cb = c ^ (row&7)
  __shared__ __align__(16) unsigned short sV[64 * 32];       // V chunk, slot cb = c ^ ((row^(row>>2))&3)
  __shared__ __align__(16) unsigned short sP[4][2][2][640];  // [wave][dbuf][qtile][16 x 40]
  __shared__ __align__(16) unsigned short sPv[1024];
  __shared__ float sD[4][32];
  const int bid = blockIdx.x;
  const int bh = bid % 96, qt = bid / 96;  // bh-fast for XCD L2 locality
  const int b = bh / 12, h = bh % 12;
  const int tid = threadIdx.x;
  const int wave = tid >> 6, lane = tid & 63;
  const int qd = lane >> 4, l15 = lane & 15;
  const int q0 = qt * 128 + wave * 32;
  const unsigned short* qb = qkv + (long)(b * 1024 + q0 + l15) * 2304 + h * 64 + qd * 8;
  bf16x8 qf00 = *(const bf16x8*)qb;  // Q pre-scaled by 0.125*log2e
  bf16x8 qf01 = *(const bf16x8*)(qb + 32);
  bf16x8 qf10 = *(const bf16x8*)(qb + (long)16 * 2304);
  bf16x8 qf11 = *(const bf16x8*)(qb + (long)16 * 2304 + 32);
  if (tid < 128) *(float4*)(sPv + tid * 8) = *(const float4*)(pbf + b * 1024 + tid * 8);
  // K staging: lane -> row = wave*8 + (lane>>3), slot = lane&7, global cb = slot ^ (row&7)
  const int krow = wave * 8 + (lane >> 3);
  const int kcb = (lane & 7) ^ (lane >> 3);
  const unsigned short* kgl = qkv + (long)(b * 1024 + krow) * 2304 + 768 + h * 64 + kcb * 8;
  // V staging: row = tid>>2 (d), slot = tid&3, global cb = slot ^ ((row^(row>>2))&3)
  const int vrow = tid >> 2;
  const int vcb = (tid & 3) ^ ((vrow ^ (vrow >> 2)) & 3);
  const unsigned short* vgl = vTp + (long)(bh * 64 + vrow) * 1024 + vcb * 8;
  const int x7 = l15 & 7;
  const int vsw = (qd ^ ((l15 ^ (l15 >> 2)) & 3)) * 8;  // V fragment swizzled col-block offset
  floatx4 O0[4] = {}, O1[4] = {};
  floatx4 Dl0 = {}, Dl1 = {};
  for (int it = 0; it < 32; ++it) {
    const int c0 = it * 32;
    __syncthreads();
    gll16(kgl + (long)c0 * 2304, sK + wave * 512);
    gll16(vgl + c0, sV + wave * 512);
    __syncthreads();
    bf16x8 k00 = *(const bf16x8*)&sK[(0 * 16 + l15) * 64 + ((0 * 4 + qd) ^ x7) * 8];
    bf16x8 k01 = *(const bf16x8*)&sK[(0 * 16 + l15) * 64 + ((1 * 4 + qd) ^ x7) * 8];
    bf16x8 k10 = *(const bf16x8*)&sK[(1 * 16 + l15) * 64 + ((0 * 4 + qd) ^ x7) * 8];
    bf16x8 k11 = *(const bf16x8*)&sK[(1 * 16 + l15) * 64 + ((1 * 4 + qd) ^ x7) * 8];
    bf16x8 pv = *(const bf16x8*)&sPv[c0 + qd * 8];
    floatx4 z = {0.f, 0.f, 0.f, 0.f};
    floatx4 s00 = mfma16(qf01, k01, mfma16(qf00, k00, z));  // q-tile 0, ctx-tile 0
    floatx4 s01 = mfma16(qf01, k11, mfma16(qf00, k10, z));  // q-tile 0, ctx-tile 1
    floatx4 s10 = mfma16(qf11, k01, mfma16(qf10, k00, z));
    floatx4 s11 = mfma16(qf11, k11, mfma16(qf10, k10, z));
    unsigned short* w0 = &sP[wave][it & 1][0][0];
    unsigned short* w1 = &sP[wave][it & 1][1][0];
#pragma unroll
    for (int r = 0; r < 4; r++) {
      const int row = qd * 4 + r;
      ((unsigned*)w0)[row * 20 + l15] = pk2bf(exp2f(s00[r]), exp2f(s01[r]));
      ((unsigned*)w1)[row * 20 + l15] = pk2bf(exp2f(s10[r]), exp2f(s11[r]));
    }
    bf16x8 pf0 = *(const bf16x8*)&w0[l15 * 40 + qd * 8];
    bf16x8 pf1 = *(const bf16x8*)&w1[l15 * 40 + qd * 8];
    bf16x8 vf0 = *(const bf16x8*)&sV[(0 * 16 + l15) * 32 + vsw];
    bf16x8 vf1 = *(const bf16x8*)&sV[(1 * 16 + l15) * 32 + vsw];
    bf16x8 vf2 = *(const bf16x8*)&sV[(2 * 16 + l15) * 32 + vsw];
    bf16x8 vf3 = *(const bf16x8*)&sV[(3 * 16 + l15) * 32 + vsw];
    Dl0 = mfma16(pf0, pv, Dl0);
    Dl1 = mfma16(pf1, pv, Dl1);
    O0[0] = mfma16(pf0, vf0, O0[0]); O1[0] = mfma16(pf1, vf0, O1[0]);
    O0[1] = mfma16(pf0, vf1, O0[1]); O1[1] = mfma16(pf1, vf1, O1[1]);
    O0[2] = mfma16(pf0, vf2, O0[2]); O1[2] = mfma16(pf1, vf2, O1[2]);
    O0[3] = mfma16(pf0, vf3, O0[3]); O1[3] = mfma16(pf1, vf3, O1[3]);
  }
  // ---- diagonal correction: O[q] += e_qq(1-p_q) V[q]; l_q += e_qq(1-p_q) ----
  {
    const unsigned short* kd = qkv + (long)(b * 1024 + q0 + l15) * 2304 + 768 + h * 64 + qd * 8;
    bf16x8 kd00 = *(const bf16x8*)kd;
    bf16x8 kd01 = *(const bf16x8*)(kd + 32);
    bf16x8 kd10 = *(const bf16x8*)(kd + (long)16 * 2304);
    bf16x8 kd11 = *(const bf16x8*)(kd + (long)16 * 2304 + 32);
    float part0 = 0.f, part1 = 0.f;
#pragma unroll
    for (int jj = 0; jj < 8; jj++) {
      part0 += (float)qf00[jj] * (float)kd00[jj] + (float)qf01[jj] * (float)kd01[jj];
      part1 += (float)qf10[jj] * (float)kd10[jj] + (float)qf11[jj] * (float)kd11[jj];
    }
    part0 += __shfl_xor(part0, 16); part0 += __shfl_xor(part0, 32);
    part1 += __shfl_xor(part1, 16); part1 += __shfl_xor(part1, 32);
    const float p0 = policy[b * 1024 + q0 + l15];
    const float p1 = policy[b * 1024 + q0 + 16 + l15];
    if (qd == 0) {
      sD[wave][l15] = exp2f(part0) * (1.0f - p0);
      sD[wave][16 + l15] = exp2f(part1) * (1.0f - p1);
    }
    __builtin_amdgcn_s_waitcnt(0);
    const unsigned short* vdiag = qkv + (long)(b * 1024 + q0) * 2304 + 1536 + h * 64 + l15;
#pragma unroll
    for (int r = 0; r < 4; r++) {
      const int row = qd * 4 + r;
      const float c0v = sD[wave][row], c1v = sD[wave][16 + row];
#pragma unroll
      for (int j = 0; j < 4; j++) {
        O0[j][r] += c0v * bf2f(vdiag[(long)row * 2304 + j * 16]);
        O1[j][r] += c1v * bf2f(vdiag[(long)(16 + row) * 2304 + j * 16]);
      }
      Dl0[r] += c0v;
      Dl1[r] += c1v;
    }
  }
  const long ob = (long)(b * 1024 + q0 + qd * 4) * 768 + h * 64 + l15;
#pragma unroll
  for (int r = 0; r < 4; r++) {
    const float li0 = 1.0f / (Dl0[r] + EPSF);
    const float li1 = 1.0f / (Dl1[r] + EPSF);
#pragma unroll
    for (int j = 0; j < 4; j++) {
      aout[ob + (long)r * 768 + j * 16] = f2bf(O0[j][r] * li0);
      aout[ob + (long)(16 * 768) + r * 768 + j * 16] = f2bf(O1[j][r] * li1);
    }
  }
}

extern "C" void kernel_launch(void* const* d_in, const int* in_sizes, int n_in,
                              void* d_out, int out_size, void* d_ws, size_t ws_size,
                              hipStream_t stream) {
  const float* x      = (const float*)d_in[0];   // [8,1024,768]
  const float* policy = (const float*)d_in[1];   // [8,1024,1]
  const float* qkv_w  = (const float*)d_in[2];   // [2304,768]
  const float* proj_w = (const float*)d_in[3];   // [768,768]
  const float* proj_b = (const float*)d_in[4];   // [768]
  float* out = (float*)d_out;                    // [8,1024,768] fp32

  char* ws = (char*)d_ws;
  unsigned short* xb    = (unsigned short*)(ws + 0);         // 12,582,912 B
  unsigned short* wqkv  = (unsigned short*)(ws + 12582912);  //  3,538,944 B
  unsigned short* wproj = (unsigned short*)(ws + 16121856);  //  1,179,648 B
  unsigned short* qkvb  = (unsigned short*)(ws + 17301504);  // 37,748,736 B
  unsigned short* vTp   = (unsigned short*)(ws + 55050240);  // 12,582,912 B
  unsigned short* aoutb = (unsigned short*)(ws + 67633152);  // 12,582,912 B
  unsigned short* pbf   = (unsigned short*)(ws + 80216064);  //     16,384 B

  cast_bf16_kernel<<<3072, 256, 0, stream>>>(x, xb, 6291456, 0);
  cast_bf16_kernel<<<864, 256, 0, stream>>>(qkv_w, wqkv, 1769472, 589824);  // Q rows *0.125*log2e
  cast_bf16_kernel<<<288, 256, 0, stream>>>(proj_w, wproj, 589824, 0);
  policy_pack<<<32, 256, 0, stream>>>(policy, pbf);
  gemm_bt<0, 128><<<dim3(18, 64), 256, 0, stream>>>(xb, wqkv, qkvb, nullptr, 8192, 2304, 768);
  transpose_v<<<dim3(16, 96), 256, 0, stream>>>(qkvb, policy, vTp);
  attn_kernel<<<dim3(768), 256, 0, stream>>>(qkvb, vTp, pbf, policy, aoutb);
  gemm_bt<1, 64><<<dim3(12, 64), 256, 0, stream>>>(aoutb, wproj, out, proj_b, 8192, 768, 768);
}

// Round 8
// 199.933 us; speedup vs baseline: 1.7267x; 1.0597x over previous
//
#include <hip/hip_runtime.h>

typedef __bf16 bf16x8 __attribute__((ext_vector_type(8)));
typedef float floatx4 __attribute__((ext_vector_type(4)));

#define EPSF 1e-6f

__device__ inline unsigned short f2bf(float f) {  // RNE
  union { float f; unsigned u; } x; x.f = f;
  unsigned r = x.u + 0x7FFFu + ((x.u >> 16) & 1u);
  return (unsigned short)(r >> 16);
}
__device__ inline float bf2f(unsigned short u) {
  union { unsigned u; float f; } x; x.u = ((unsigned)u) << 16;
  return x.f;
}
// pack two f32 -> bf16x2 dword, round-half-up
__device__ inline unsigned pk2bf(float lo, float hi) {
  union { float f; unsigned u; } a, b; a.f = lo; b.f = hi;
  unsigned ua = a.u + 0x8000u, ub = b.u + 0x8000u;
  return (ub & 0xFFFF0000u) | (ua >> 16);
}

__device__ inline floatx4 mfma16(bf16x8 a, bf16x8 b, floatx4 c) {
  return __builtin_amdgcn_mfma_f32_16x16x32_bf16(a, b, c, 0, 0, 0);
}

__device__ inline void gll16(const unsigned short* g, unsigned short* l) {
  __builtin_amdgcn_global_load_lds((__attribute__((address_space(1))) void*)g,
                                   (__attribute__((address_space(3))) void*)l, 16, 0, 0);
}

// ---------- merged prep: x cast | qkv_w cast (Q-scaled) | proj_w cast with k-dim gather-perm | policy pack ----------
// perm pi(c) = 4*(c%16) + c/16 within each 64-block: qkvb stored col' holds original c = 16*(c'&3) + (c'>>2)
__global__ __launch_bounds__(256) void prep_kernel(const float* __restrict__ x,
                                                   const float* __restrict__ qkv_w,
                                                   const float* __restrict__ proj_w,
                                                   const float* __restrict__ policy,
                                                   unsigned short* __restrict__ xb,
                                                   unsigned short* __restrict__ wqkv,
                                                   unsigned short* __restrict__ wproj,
                                                   unsigned short* __restrict__ pbf) {
  const int bid = blockIdx.x, tid = threadIdx.x;
  if (bid < 3072) {  // x cast: 6291456 elems
    const int i = bid * 2048 + tid * 8;
    float4 v0 = *(const float4*)(x + i);
    float4 v1 = *(const float4*)(x + i + 4);
    __align__(16) unsigned short o[8] = {f2bf(v0.x), f2bf(v0.y), f2bf(v0.z), f2bf(v0.w),
                                         f2bf(v1.x), f2bf(v1.y), f2bf(v1.z), f2bf(v1.w)};
    *(float4*)(xb + i) = *(float4*)o;
  } else if (bid < 3936) {  // qkv_w cast: 1769472 elems, first 589824 (Q rows) * 0.125*log2(e)
    const int i = (bid - 3072) * 2048 + tid * 8;
    const float s = (i < 589824) ? 0.18033688011112042f : 1.0f;
    float4 v0 = *(const float4*)(qkv_w + i);
    float4 v1 = *(const float4*)(qkv_w + i + 4);
    __align__(16) unsigned short o[8] = {
        f2bf(v0.x * s), f2bf(v0.y * s), f2bf(v0.z * s), f2bf(v0.w * s),
        f2bf(v1.x * s), f2bf(v1.y * s), f2bf(v1.z * s), f2bf(v1.w * s)};
    *(float4*)(wqkv + i) = *(float4*)o;
  } else if (bid < 4224) {  // proj_w cast with in-dim perm: 589824 elems
    const int i0 = (bid - 3936) * 2048 + tid * 8;  // dest index (row-contig)
    const int base = (i0 / 768) * 768 + ((i0 % 768) & ~63);
    __align__(16) unsigned short o[8];
#pragma unroll
    for (int t = 0; t < 8; t++) {
      const int cp = (i0 + t) & 63;                 // stored position within 64-block
      const int c = 16 * (cp & 3) + (cp >> 2);      // original column
      o[t] = f2bf(proj_w[base + c]);
    }
    *(float4*)(wproj + i0) = *(float4*)o;
  } else {  // policy pack: 8192 elems, ctx-perm col' = (c%16)*2 + c/16 per 32-chunk
    const int idx = (bid - 4224) * 256 + tid;
    const int b = idx >> 10, g = idx & 1023;
    const int chunk = g >> 5, w = g & 31;
    const int c = (chunk << 5) + (w >> 1) + ((w & 1) << 4);
    pbf[idx] = f2bf(policy[b * 1024 + c]);
  }
}

// ---------- bf16 GEMM: C[M,N] = A[M,K]*Bt[N,K]^T ; BK=64, XOR-swizzled LDS ----------
// EP=0 (BN=128): bf16 out with 64-block col-perm pi (packed dwordx2 stores).
// EP=1 (BN=64): f32 out + bias, natural layout.
template <int EP, int BN>
__global__ __launch_bounds__(256, 3) void gemm_bt(const unsigned short* __restrict__ A,
                                                  const unsigned short* __restrict__ Bt,
                                                  void* __restrict__ Cout,
                                                  const float* __restrict__ bias,
                                                  int M, int N, int K) {
  constexpr int J = BN / 32;
  __shared__ __align__(16) unsigned short sA[128 * 64];
  __shared__ __align__(16) unsigned short sB[BN * 64];
  const int m0 = blockIdx.y * 128, n0 = blockIdx.x * BN;
  const int tid = threadIdx.x;
  const int lane = tid & 63, wave = tid >> 6;
  const int qd = lane >> 4, l15 = lane & 15;
  const int wr = (wave >> 1) * 64, wc = (wave & 1) * (BN / 2);
  const int srow = tid >> 3;
  const int scb = (tid & 7) ^ (srow & 7);
  const unsigned short* Ag = A + (long)(m0 + srow) * K + scb * 8;
  const unsigned short* Bg = Bt + (long)(n0 + srow) * K + scb * 8;
  const int x7 = l15 & 7;
  floatx4 acc[4][J] = {};
  for (int k0 = 0; k0 < K; k0 += 64) {
    __syncthreads();
#pragma unroll
    for (int p = 0; p < 4; p++) gll16(Ag + (long)(p * 32) * K + k0, sA + p * 2048 + wave * 512);
#pragma unroll
    for (int p = 0; p < J; p++) gll16(Bg + (long)(p * 32) * K + k0, sB + p * 2048 + wave * 512);
    __syncthreads();
#pragma unroll
    for (int s = 0; s < 2; s++) {
      const int cw = ((s * 4 + qd) ^ x7) * 8;
      bf16x8 af[4], bf[J];
#pragma unroll
      for (int i = 0; i < 4; i++) af[i] = *(const bf16x8*)&sA[(wr + i * 16 + l15) * 64 + cw];
#pragma unroll
      for (int j = 0; j < J; j++) bf[j] = *(const bf16x8*)&sB[(wc + j * 16 + l15) * 64 + cw];
#pragma unroll
      for (int i = 0; i < 4; i++)
#pragma unroll
        for (int j = 0; j < J; j++) acc[i][j] = mfma16(af[i], bf[j], acc[i][j]);
    }
  }
  if constexpr (EP == 0) {
    // feature f = wc + 16j + l15 stored at col' = wc + 4*l15 + j  (pi within 64-block)
#pragma unroll
    for (int i = 0; i < 4; i++)
#pragma unroll
      for (int r = 0; r < 4; r++) {
        const int row = m0 + wr + i * 16 + qd * 4 + r;
        __align__(8) unsigned short pk[4];
#pragma unroll
        for (int j = 0; j < 4; j++) pk[j] = f2bf(acc[i][j][r]);
        *(uint2*)((unsigned short*)Cout + (long)row * N + n0 + wc + 4 * l15) = *(uint2*)pk;
      }
  } else {
#pragma unroll
    for (int i = 0; i < 4; i++)
#pragma unroll
      for (int j = 0; j < J; j++) {
        const int col = n0 + wc + j * 16 + l15;
#pragma unroll
        for (int r = 0; r < 4; r++) {
          const int row = m0 + wr + i * 16 + qd * 4 + r;
          ((float*)Cout)[(long)row * N + col] = acc[i][j][r] + bias[col];
        }
      }
  }
}

// ---------- V transpose + policy fold + ctx-permute: vTp[bh][d'][g] = bf16(V[c(g)][d'] * p[c(g)]) ----------
__global__ __launch_bounds__(256) void transpose_v(const unsigned short* __restrict__ qkv,
                                                   const float* __restrict__ policy,
                                                   unsigned short* __restrict__ vTp) {
  __shared__ unsigned short tile[64][72];
  __shared__ float sPol[64];
  const int bh = blockIdx.y;
  const int b = bh / 12, h = bh % 12;
  const int n0 = blockIdx.x * 64;
  const int t = threadIdx.x;
  if (t < 64) sPol[t] = policy[b * 1024 + n0 + t];
  {
    const int nr = t >> 2, dc = (t & 3) * 16;
    const unsigned short* src = qkv + (long)(b * 1024 + n0 + nr) * 2304 + 2 * 768 + h * 64 + dc;
    float4 v0 = *(const float4*)src;
    float4 v1 = *(const float4*)(src + 8);
    *(float4*)&tile[nr][dc] = v0;
    *(float4*)&tile[nr][dc + 8] = v1;
  }
  __syncthreads();
  {
    const int d = t >> 2, nc = (t & 3) * 16;
    __align__(16) unsigned short o[16];
#pragma unroll
    for (int jj = 0; jj < 16; jj++) {
      const int cc = nc + jj;
      const int w = cc & 31;
      const int cl = (cc & 32) + (w >> 1) + ((w & 1) << 4);
      o[jj] = f2bf(bf2f(tile[cl][d]) * sPol[cl]);
    }
    unsigned short* dst = vTp + (long)(bh * 64 + d) * 1024 + n0 + nc;
    *(float4*)dst = *(float4*)&o[0];
    *(float4*)(dst + 8) = *(float4*)&o[8];
  }
}

// ---------- attention v6b: prefetch pipeline, one barrier/iter with EXPLICIT vmcnt drain ----------
// Race fix vs v6: vmcnt is per-wave; cross-wave visibility of global_load_lds DMA requires this
// wave's vmcnt(0) BEFORE s_barrier. Emit it explicitly — the prefetch still overlaps the whole
// compute body (issued at top of iter, drained at bottom).
__global__ __launch_bounds__(256, 3) void attn_kernel(const unsigned short* __restrict__ qkv,
                                                      const unsigned short* __restrict__ vTp,
                                                      const unsigned short* __restrict__ pbf,
                                                      const float* __restrict__ policy,
                                                      unsigned short* __restrict__ aout) {
  __shared__ __align__(16) unsigned short sK[2][2048];       // 32 ctx x 64 d, slot cb = c ^ (row&7)
  __shared__ __align__(16) unsigned short sV[2][2048];       // 64 d x 32 ctx, slot cb = c ^ ((row^(row>>2))&3)
  __shared__ __align__(16) unsigned short sP[4][2][2][640];  // [wave][dbuf][qtile][16 x 40]
  __shared__ __align__(16) unsigned short sPv[1024];
  __shared__ float sD[4][32];
  const int bid = blockIdx.x;
  const int bh = bid % 96, qt = bid / 96;  // bh-fast for XCD L2 locality
  const int b = bh / 12, h = bh % 12;
  const int tid = threadIdx.x;
  const int wave = tid >> 6, lane = tid & 63;
  const int qd = lane >> 4, l15 = lane & 15;
  const int q0 = qt * 128 + wave * 32;
  const unsigned short* qb = qkv + (long)(b * 1024 + q0 + l15) * 2304 + h * 64 + qd * 8;
  bf16x8 qf00 = *(const bf16x8*)qb;  // Q pre-scaled by 0.125*log2e
  bf16x8 qf01 = *(const bf16x8*)(qb + 32);
  bf16x8 qf10 = *(const bf16x8*)(qb + (long)16 * 2304);
  bf16x8 qf11 = *(const bf16x8*)(qb + (long)16 * 2304 + 32);
  if (tid < 128) *(float4*)(sPv + tid * 8) = *(const float4*)(pbf + b * 1024 + tid * 8);
  const int krow = wave * 8 + (lane >> 3);
  const int kcb = (lane & 7) ^ (lane >> 3);
  const unsigned short* kgl = qkv + (long)(b * 1024 + krow) * 2304 + 768 + h * 64 + kcb * 8;
  const int vrow = tid >> 2;
  const int vcb = (tid & 3) ^ ((vrow ^ (vrow >> 2)) & 3);
  const unsigned short* vgl = vTp + (long)(bh * 64 + vrow) * 1024 + vcb * 8;
  const int x7 = l15 & 7;
  const int vsw = (qd ^ ((l15 ^ (l15 >> 2)) & 3)) * 8;
  floatx4 O0[4] = {}, O1[4] = {};
  floatx4 Dl0 = {}, Dl1 = {};
  // prologue: stage chunk 0 into buf 0, publish to all waves
  gll16(kgl, &sK[0][wave * 512]);
  gll16(vgl, &sV[0][wave * 512]);
  __builtin_amdgcn_s_waitcnt(0);  // drain own DMA before barrier (cross-wave publish)
  __syncthreads();
  for (int it = 0; it < 32; ++it) {
    const int buf = it & 1;
    if (it < 31) {  // prefetch chunk it+1 — in flight across this iteration's full compute
      gll16(kgl + (long)(32 * (it + 1)) * 2304, &sK[buf ^ 1][wave * 512]);
      gll16(vgl + 32 * (it + 1), &sV[buf ^ 1][wave * 512]);
    }
    const int c0 = it * 32;
    bf16x8 k00 = *(const bf16x8*)&sK[buf][(0 * 16 + l15) * 64 + ((0 * 4 + qd) ^ x7) * 8];
    bf16x8 k01 = *(const bf16x8*)&sK[buf][(0 * 16 + l15) * 64 + ((1 * 4 + qd) ^ x7) * 8];
    bf16x8 k10 = *(const bf16x8*)&sK[buf][(1 * 16 + l15) * 64 + ((0 * 4 + qd) ^ x7) * 8];
    bf16x8 k11 = *(const bf16x8*)&sK[buf][(1 * 16 + l15) * 64 + ((1 * 4 + qd) ^ x7) * 8];
    bf16x8 pv = *(const bf16x8*)&sPv[c0 + qd * 8];
    floatx4 z = {0.f, 0.f, 0.f, 0.f};
    floatx4 s00 = mfma16(qf01, k01, mfma16(qf00, k00, z));
    floatx4 s01 = mfma16(qf01, k11, mfma16(qf00, k10, z));
    floatx4 s10 = mfma16(qf11, k01, mfma16(qf10, k00, z));
    floatx4 s11 = mfma16(qf11, k11, mfma16(qf10, k10, z));
    unsigned short* w0 = &sP[wave][buf][0][0];
    unsigned short* w1 = &sP[wave][buf][1][0];
#pragma unroll
    for (int r = 0; r < 4; r++) {
      const int row = qd * 4 + r;
      ((unsigned*)w0)[row * 20 + l15] = pk2bf(exp2f(s00[r]), exp2f(s01[r]));
      ((unsigned*)w1)[row * 20 + l15] = pk2bf(exp2f(s10[r]), exp2f(s11[r]));
    }
    bf16x8 pf0 = *(const bf16x8*)&w0[l15 * 40 + qd * 8];
    bf16x8 pf1 = *(const bf16x8*)&w1[l15 * 40 + qd * 8];
    bf16x8 vf0 = *(const bf16x8*)&sV[buf][(0 * 16 + l15) * 32 + vsw];
    bf16x8 vf1 = *(const bf16x8*)&sV[buf][(1 * 16 + l15) * 32 + vsw];
    bf16x8 vf2 = *(const bf16x8*)&sV[buf][(2 * 16 + l15) * 32 + vsw];
    bf16x8 vf3 = *(const bf16x8*)&sV[buf][(3 * 16 + l15) * 32 + vsw];
    Dl0 = mfma16(pf0, pv, Dl0);
    Dl1 = mfma16(pf1, pv, Dl1);
    O0[0] = mfma16(pf0, vf0, O0[0]); O1[0] = mfma16(pf1, vf0, O1[0]);
    O0[1] = mfma16(pf0, vf1, O0[1]); O1[1] = mfma16(pf1, vf1, O1[1]);
    O0[2] = mfma16(pf0, vf2, O0[2]); O1[2] = mfma16(pf1, vf2, O1[2]);
    O0[3] = mfma16(pf0, vf3, O0[3]); O1[3] = mfma16(pf1, vf3, O1[3]);
    __builtin_amdgcn_s_waitcnt(0);  // drain own prefetch DMA before barrier (cross-wave publish)
    __syncthreads();                // also: all waves done reading buf -> safe to overwrite next iter
  }
  // ---- diagonal correction: O[q] += e_qq(1-p_q) V[q]; l_q += e_qq(1-p_q) ----
  {
    const unsigned short* kd = qkv + (long)(b * 1024 + q0 + l15) * 2304 + 768 + h * 64 + qd * 8;
    bf16x8 kd00 = *(const bf16x8*)kd;
    bf16x8 kd01 = *(const bf16x8*)(kd + 32);
    bf16x8 kd10 = *(const bf16x8*)(kd + (long)16 * 2304);
    bf16x8 kd11 = *(const bf16x8*)(kd + (long)16 * 2304 + 32);
    float part0 = 0.f, part1 = 0.f;
#pragma unroll
    for (int jj = 0; jj < 8; jj++) {
      part0 += (float)qf00[jj] * (float)kd00[jj] + (float)qf01[jj] * (float)kd01[jj];
      part1 += (float)qf10[jj] * (float)kd10[jj] + (float)qf11[jj] * (float)kd11[jj];
    }
    part0 += __shfl_xor(part0, 16); part0 += __shfl_xor(part0, 32);
    part1 += __shfl_xor(part1, 16); part1 += __shfl_xor(part1, 32);
    const float p0 = policy[b * 1024 + q0 + l15];
    const float p1 = policy[b * 1024 + q0 + 16 + l15];
    if (qd == 0) {
      sD[wave][l15] = exp2f(part0) * (1.0f - p0);
      sD[wave][16 + l15] = exp2f(part1) * (1.0f - p1);
    }
    __builtin_amdgcn_s_waitcnt(0);
    const unsigned short* vdiag = qkv + (long)(b * 1024 + q0) * 2304 + 1536 + h * 64 + l15;
#pragma unroll
    for (int r = 0; r < 4; r++) {
      const int row = qd * 4 + r;
      const float c0v = sD[wave][row], c1v = sD[wave][16 + row];
#pragma unroll
      for (int j = 0; j < 4; j++) {
        O0[j][r] += c0v * bf2f(vdiag[(long)row * 2304 + j * 16]);
        O1[j][r] += c1v * bf2f(vdiag[(long)(16 + row) * 2304 + j * 16]);
      }
      Dl0[r] += c0v;
      Dl1[r] += c1v;
    }
  }
  const long ob = (long)(b * 1024 + q0 + qd * 4) * 768 + h * 64 + l15;
#pragma unroll
  for (int r = 0; r < 4; r++) {
    const float li0 = 1.0f / (Dl0[r] + EPSF);
    const float li1 = 1.0f / (Dl1[r] + EPSF);
#pragma unroll
    for (int j = 0; j < 4; j++) {
      aout[ob + (long)r * 768 + j * 16] = f2bf(O0[j][r] * li0);
      aout[ob + (long)(16 * 768) + r * 768 + j * 16] = f2bf(O1[j][r] * li1);
    }
  }
}

extern "C" void kernel_launch(void* const* d_in, const int* in_sizes, int n_in,
                              void* d_out, int out_size, void* d_ws, size_t ws_size,
                              hipStream_t stream) {
  const float* x      = (const float*)d_in[0];   // [8,1024,768]
  const float* policy = (const float*)d_in[1];   // [8,1024,1]
  const float* qkv_w  = (const float*)d_in[2];   // [2304,768]
  const float* proj_w = (const float*)d_in[3];   // [768,768]
  const float* proj_b = (const float*)d_in[4];   // [768]
  float* out = (float*)d_out;                    // [8,1024,768] fp32

  char* ws = (char*)d_ws;
  unsigned short* xb    = (unsigned short*)(ws + 0);         // 12,582,912 B
  unsigned short* wqkv  = (unsigned short*)(ws + 12582912);  //  3,538,944 B
  unsigned short* wproj = (unsigned short*)(ws + 16121856);  //  1,179,648 B
  unsigned short* qkvb  = (unsigned short*)(ws + 17301504);  // 37,748,736 B
  unsigned short* vTp   = (unsigned short*)(ws + 55050240);  // 12,582,912 B
  unsigned short* aoutb = (unsigned short*)(ws + 67633152);  // 12,582,912 B
  unsigned short* pbf   = (unsigned short*)(ws + 80216064);  //     16,384 B

  prep_kernel<<<4256, 256, 0, stream>>>(x, qkv_w, proj_w, policy, xb, wqkv, wproj, pbf);
  gemm_bt<0, 128><<<dim3(18, 64), 256, 0, stream>>>(xb, wqkv, qkvb, nullptr, 8192, 2304, 768);
  transpose_v<<<dim3(16, 96), 256, 0, stream>>>(qkvb, policy, vTp);
  attn_kernel<<<dim3(768), 256, 0, stream>>>(qkvb, vTp, pbf, policy, aoutb);
  gemm_bt<1, 64><<<dim3(12, 64), 256, 0, stream>>>(aoutb, wproj, out, proj_b, 8192, 768, 768);
}